// Round 8
// baseline (98.243 us; speedup 1.0000x reference)
//
#include <hip/hip_runtime.h>

typedef unsigned short ushort_t;
typedef __attribute__((ext_vector_type(8))) short bf16x8;
typedef __attribute__((ext_vector_type(8))) _Float16 f16x8;
typedef __attribute__((ext_vector_type(16))) float f32x16;

#define NORMC 0.35355339059327373f   // 64^-0.25
#define DIAGC 0.0625f                // 0.5 * 64^-0.5
#define RATIO 0.0625f                // 256^-0.5
#define KEPS  1e-4f
#define AEPS  1e-6f
#define KAPPA (RATIO*KEPS)

__device__ __forceinline__ unsigned short f2bf(float f){
  unsigned u = __float_as_uint(f);
  unsigned r = (u + 0x7FFFu + ((u >> 16) & 1u)) >> 16;  // RNE
  return (unsigned short)r;
}
__device__ __forceinline__ float bf2f(unsigned short h){
  return __uint_as_float(((unsigned)h) << 16);
}
__device__ __forceinline__ unsigned enc_f(float f){
  unsigned u = __float_as_uint(f);
  return (u & 0x80000000u) ? ~u : (u | 0x80000000u);
}
__device__ __forceinline__ float dec_f(unsigned e){
  unsigned b = (e & 0x80000000u) ? (e ^ 0x80000000u) : ~e;
  return __uint_as_float(b);
}
__device__ __forceinline__ unsigned short h2u(_Float16 h){
  union { _Float16 h; unsigned short u; } c; c.h = h; return c.u;
}
__device__ __forceinline__ unsigned pk2h(float a, float b){
  return (unsigned)h2u((_Float16)a) | ((unsigned)h2u((_Float16)b) << 16);
}
// corrected-kf transform: bf16(alpha*bf2f(x)+kappa) for both halves of a packed word
__device__ __forceinline__ unsigned cvt2(unsigned wrd, float alpha){
  float lo = bf2f((ushort_t)(wrd & 0xffffu));
  float hi = bf2f((ushort_t)(wrd >> 16));
  return (unsigned)f2bf(fmaf(alpha, lo, KAPPA)) |
         ((unsigned)f2bf(fmaf(alpha, hi, KAPPA)) << 16);
}

// K0: proj -> fp16 (NORMC-scaled), layout [m][d]; init global-max slot
__global__ void k_prep(const float* __restrict__ proj, ushort_t* __restrict__ pjh,
                       unsigned* __restrict__ kmax){
  int t = threadIdx.x;   // m
  if (t == 0) *kmax = 0u;
  for (int d = 0; d < 64; ++d){
    float val = NORMC * proj[t*64 + d];
    pjh[t*64 + d] = h2u((_Float16)val);
  }
}

// K_A: k-feature GEMM + per-chunk sums (fused). One block per chunk, 512 thr / 8 waves.
// Writes kfpre (global), Sl_pre (fp32), Zl_pre, vsum, lmArr, atomicMax gm.
__launch_bounds__(512, 2)
__global__ void k_chunkF(const float* __restrict__ kk, const float* __restrict__ v,
                         const ushort_t* __restrict__ pjh,
                         ushort_t* __restrict__ kfp, float* __restrict__ Zl,
                         float* __restrict__ Sl, float* __restrict__ vsb,
                         unsigned* __restrict__ kmax, float* __restrict__ lmArr)
{
  extern __shared__ char sm[];
  char* Bp = sm;                        // proj frag-packed [0,32K)
  char* Xh = sm + 32768;                // x-hi frags [32K,48K)
  char* Xl = sm + 49152;                // x-lo frags [48K,64K)
  char* ob = sm;                        // epilogue kfp staging alias [0,64K)
  char* kT = sm + 65536;                // [256 m][256B c] bf16, swz ^((m&15)<<4)
  char* vT = sm + 131072;               // [64 e][256B c] bf16, swz ^((e&15)<<4)
  float* dsm  = (float*)(sm + 147456);  // [128]
  float* wred = (float*)(sm + 147968);  // [8]

  int tid = threadIdx.x;
  int w   = tid >> 6;
  int wr  = w & 3;
  int wc  = w >> 2;
  int lane= tid & 63;
  int l31 = lane & 31;
  int half= lane >> 5;
  int cb  = (int)blockIdx.x;
  int bh  = cb >> 5, j = cb & 31;
  int row0 = bh*4096 + j*128;

  // stage proj frags
  for (int i = tid; i < 2048; i += 512){
    int m = i >> 3, c8 = i & 7;
    int rgn = ((m>>5)*4 + (c8>>1))*2 + (c8&1);
    int slot = (m & 31) ^ ((rgn & 7) << 2);
    *(uint4*)(Bp + rgn*512 + slot*16) = *(const uint4*)(pjh + m*64 + c8*8);
  }
  // stage x = k-chunk frags (fp16 hi/lo) + dsm
  #pragma unroll
  for (int it = 0; it < 4; ++it){
    int g = it*512 + tid;
    int row = g >> 4, c4 = g & 15;
    float4 xv = *(const float4*)(kk + (size_t)(row0+row)*64 + c4*4);
    _Float16 h0=(_Float16)xv.x, h1=(_Float16)xv.y, h2=(_Float16)xv.z, h3=(_Float16)xv.w;
    float l0 = xv.x-(float)h0, l1 = xv.y-(float)h1, l2 = xv.z-(float)h2, l3 = xv.w-(float)h3;
    int rgn = ((row>>5)*4 + (c4>>2))*2 + ((c4>>1)&1);
    int off = rgn*512 + (((row&31) ^ ((c4>>1)<<2)))*16 + (c4&1)*8;
    uint2 ph; ph.x = (unsigned)h2u(h0)|((unsigned)h2u(h1)<<16);
              ph.y = (unsigned)h2u(h2)|((unsigned)h2u(h3)<<16);
    uint2 pl; pl.x = pk2h(l0,l1); pl.y = pk2h(l2,l3);
    *(uint2*)(Xh + off) = ph;
    *(uint2*)(Xl + off) = pl;
    float ssq = xv.x*xv.x + xv.y*xv.y + xv.z*xv.z + xv.w*xv.w;
    ssq += __shfl_xor(ssq, 1); ssq += __shfl_xor(ssq, 2);
    ssq += __shfl_xor(ssq, 4); ssq += __shfl_xor(ssq, 8);
    if ((tid & 15) == 0) dsm[row] = ssq;
  }
  // stage vT (bf16 transposed)
  {
    int e = tid & 63, c0 = tid >> 6;
    int swz = (e & 15) << 4;
    #pragma unroll
    for (int u=0; u<16; ++u){
      int c = c0 + u*8;
      *(ushort_t*)(vT + e*256 + ((c*2) ^ swz)) = f2bf(v[(size_t)(row0+c)*64 + e]);
    }
  }
  __syncthreads();

  // k-dash (fp16 2-term)
  f16x8 ah[4], al[4];
  #pragma unroll
  for (int ks = 0; ks < 4; ++ks){
    int rgn = (wr*4+ks)*2+half;
    int off = rgn*512 + ((l31 ^ ((2*ks+half)<<2)))*16;
    ah[ks] = *(const f16x8*)(Xh + off);
    al[ks] = *(const f16x8*)(Xl + off);
  }
  f32x16 acc[4];
  #pragma unroll
  for (int ct=0; ct<4; ++ct){
    #pragma unroll
    for (int r=0; r<16; ++r) acc[ct][r] = 0.f;
  }
  #pragma unroll
  for (int ks = 0; ks < 4; ++ks){
    #pragma unroll
    for (int ct=0; ct<4; ++ct){
      int ctg = wc*4 + ct;
      int rgn = (ctg*4+ks)*2+half;
      f16x8 bv = *(const f16x8*)(Bp + rgn*512 + ((l31 ^ ((2*ks+half)<<2)))*16);
      acc[ct] = __builtin_amdgcn_mfma_f32_32x32x16_f16(ah[ks], bv, acc[ct], 0, 0, 0);
      acc[ct] = __builtin_amdgcn_mfma_f32_32x32x16_f16(al[ks], bv, acc[ct], 0, 0, 0);
    }
  }

  // block max
  {
    float wm = acc[0][0];
    #pragma unroll
    for (int ct=0; ct<4; ++ct){
      #pragma unroll
      for (int r=0; r<16; ++r) wm = fmaxf(wm, acc[ct][r]);
    }
    #pragma unroll
    for (int s=1; s<32; s<<=1) wm = fmaxf(wm, __shfl_xor(wm, s));
    wm = fmaxf(wm, __shfl_xor(wm, 32));
    if (lane == 0) wred[w] = wm;
  }
  __syncthreads();
  float lmb = wred[0];
  #pragma unroll
  for (int i=1;i<8;++i) lmb = fmaxf(lmb, wred[i]);
  if (tid == 0){
    lmArr[cb] = lmb;
    atomicMax(kmax, enc_f(lmb));
  }
  float dgv[16];
  #pragma unroll
  for (int r=0; r<16; ++r)
    dgv[r] = DIAGC * dsm[32*wr + (r&3) + 8*(r>>2) + 4*half];

  // epilogue: kfpre -> ob (for global store) and kT (transposed, for GEMM)
  #pragma unroll
  for (int ct=0; ct<4; ++ct){
    int m = wc*128 + ct*32 + l31;
    int swm = (m & 15) << 4;
    #pragma unroll
    for (int g=0; g<4; ++g){
      unsigned pk0=0, pk1=0;
      #pragma unroll
      for (int rr=0; rr<4; ++rr){
        int r = g*4 + rr;
        int c = 32*wr + rr + 8*g + 4*half;
        float e = __expf(acc[ct][r] - dgv[r] - lmb);
        unsigned b = f2bf(e);
        if (rr < 2) pk0 |= b << (16*rr); else pk1 |= b << (16*(rr-2));
        *(ushort_t*)(ob + c*512 + ((m*2) ^ ((c&15)<<4))) = (ushort_t)b;
      }
      int c0 = 32*wr + 8*g + 4*half;
      *(uint2*)(kT + m*256 + ((c0*2) ^ swm)) = make_uint2(pk0, pk1);
    }
  }
  __syncthreads();

  // GEMM: Sl_pre[m][e] = sum_c kfpre[m][c]*v[c][e]; Zl_pre[m]; vsum[e] (wave 0)
  f32x16 acc2[2], accz, avs[2];
  #pragma unroll
  for (int et=0;et<2;++et){
    #pragma unroll
    for (int r=0;r<16;++r){ acc2[et][r]=0.f; avs[et][r]=0.f; }
  }
  #pragma unroll
  for (int r=0;r<16;++r) accz[r]=0.f;
  bf16x8 onesB, onesA;
  #pragma unroll
  for (int i=0;i<8;++i){
    onesB[i] = (l31==0) ? (short)0x3F80 : (short)0;
    onesA[i] = (short)0x3F80;
  }
  int mrow = 32*w + l31;
  int swm2 = (mrow & 15) << 4;
  #pragma unroll
  for (int ks=0; ks<8; ++ks){
    int koff = ks*32 + half*16;
    bf16x8 af = *(const bf16x8*)(kT + mrow*256 + (koff ^ swm2));
    bf16x8 b0 = *(const bf16x8*)(vT + (l31)*256      + (koff ^ ((l31&15)<<4)));
    bf16x8 b1 = *(const bf16x8*)(vT + (32+l31)*256   + (koff ^ (((32+l31)&15)<<4)));
    acc2[0] = __builtin_amdgcn_mfma_f32_32x32x16_bf16(af, b0, acc2[0], 0, 0, 0);
    acc2[1] = __builtin_amdgcn_mfma_f32_32x32x16_bf16(af, b1, acc2[1], 0, 0, 0);
    accz    = __builtin_amdgcn_mfma_f32_32x32x16_bf16(af, onesB, accz, 0, 0, 0);
    if (w == 0){
      avs[0] = __builtin_amdgcn_mfma_f32_32x32x16_bf16(onesA, b0, avs[0], 0, 0, 0);
      avs[1] = __builtin_amdgcn_mfma_f32_32x32x16_bf16(onesA, b1, avs[1], 0, 0, 0);
    }
  }
  // stores
  #pragma unroll
  for (int r=0; r<16; ++r){
    int m = 32*w + (r&3) + 8*(r>>2) + 4*half;
    #pragma unroll
    for (int et=0; et<2; ++et)
      Sl[(size_t)cb*16384 + (size_t)m*64 + et*32 + l31] = acc2[et][r];
  }
  if (l31 == 0){
    #pragma unroll
    for (int r=0; r<16; ++r){
      int m = 32*w + (r&3) + 8*(r>>2) + 4*half;
      Zl[(size_t)cb*256 + m] = accz[r];
    }
  }
  if (w == 0 && half == 0){
    vsb[(size_t)cb*64 + l31]      = avs[0][0];
    vsb[(size_t)cb*64 + 32 + l31] = avs[1][0];
  }
  // kfp global store from ob
  {
    ushort_t* dst = kfp + (size_t)row0*256;
    for (int i = tid; i < 4096; i += 512){
      int row = i >> 5, s = i & 31;
      uint4 d = *(const uint4*)(ob + row*512 + ((s*16) ^ ((row&15)<<4)));
      *(uint4*)(dst + (size_t)row*256 + ((s ^ (row&15)))*8) = d;
    }
  }
}

// K4: scan with alpha/kappa correction. grid 16*65.
__launch_bounds__(256)
__global__ void k_scan(float* __restrict__ Zl, const float* __restrict__ Sl,
                       const float* __restrict__ vsb, const float* __restrict__ lmArr,
                       const unsigned* __restrict__ kmax,
                       ushort_t* __restrict__ S0b,
                       float* __restrict__ outZ, float* __restrict__ outS){
  float gm = dec_f(*kmax);
  int t = threadIdx.x;
  int bh = blockIdx.x / 65;
  int s  = blockIdx.x % 65;
  if (s == 64){
    size_t base = (size_t)(bh*32)*256 + t;
    float rz = 0.f;
    #pragma unroll
    for (int j0=0;j0<32;j0+=8){
      float x[8];
      #pragma unroll
      for (int u=0;u<8;++u){
        int cbx = bh*32 + j0 + u;
        float a = RATIO * __expf(lmArr[cbx] - gm);
        x[u] = fmaf(a, Zl[base + (size_t)(j0+u)*256], KAPPA*128.f);
      }
      #pragma unroll
      for (int u=0;u<8;++u){ Zl[base + (size_t)(j0+u)*256] = rz; rz += x[u]; }
    }
    outZ[(size_t)bh*256 + t] = rz;
  } else {
    int e = t & 63;
    size_t base = (size_t)(bh*32)*16384 + (size_t)s*256 + t;
    float rs = 0.f;
    #pragma unroll
    for (int j0=0;j0<32;j0+=8){
      float x[8];
      #pragma unroll
      for (int u=0;u<8;++u){
        int cbx = bh*32 + j0 + u;
        float a = RATIO * __expf(lmArr[cbx] - gm);
        x[u] = fmaf(a, Sl[base + (size_t)(j0+u)*16384], KAPPA * vsb[(size_t)cbx*64 + e]);
      }
      #pragma unroll
      for (int u=0;u<8;++u){
        S0b[(size_t)(bh*32 + j0+u)*16384 + (size_t)s*256 + t] = f2bf(rs);
        rs += x[u];
      }
    }
    outS[(size_t)bh*16384 + (size_t)s*256 + t] = rs;
  }
}

// K_B: q-feature GEMM + per-chunk output (fused). One block per chunk, 512 thr / 8 waves.
__launch_bounds__(512, 2)
__global__ void k_outF(const float* __restrict__ q, const ushort_t* __restrict__ pjh,
                       const ushort_t* __restrict__ kfp, const float* __restrict__ v,
                       const ushort_t* __restrict__ S0b, const float* __restrict__ Zp,
                       const float* __restrict__ lmArr, const unsigned* __restrict__ kmax,
                       float* __restrict__ outO)
{
  extern __shared__ char sm[];
  char* Bp  = sm;                       // proj [0,32K); Ab alias after dash
  char* Ab  = sm;                       // [128][256B] bf16 swz ^((r&15)<<4)
  char* qfb = sm + 32768;               // [128 r][512B m] bf16 swz ^((r&15)<<4)
  char* Xh  = sm + 32768;               // x frags alias inside qfb
  char* Xl  = sm + 49152;
  char* ktb = sm + 98304;               // [128 r][128B] per-m-tile, swz ^((r&7)<<4)
  char* s0t = sm + 114688;              // [64 e][128B] per-m-tile
  char* vTb = sm + 98304;               // A*v phase alias: [64 e][256B]
  float* dsm = (float*)(sm + 122880);   // [128]
  float* rmx = (float*)(sm + 123392);   // [2][128]
  float* qzc = (float*)(sm + 124416);   // [2][128]
  float* rsc = (float*)(sm + 125440);   // [2][128]
  float* rsf = (float*)(sm + 126464);   // [128]

  int tid = threadIdx.x;
  int w   = tid >> 6;
  int wr  = w & 3;
  int wc  = w >> 2;
  int lane= tid & 63;
  int l31 = lane & 31;
  int half= lane >> 5;
  int pb  = (int)blockIdx.x;
  int bh  = pb >> 5, j = pb & 31;
  int row0 = bh*4096 + j*128;
  size_t qbase = (size_t)row0*256;

  float gmv = dec_f(*kmax);
  float alpha = RATIO * __expf(lmArr[pb] - gmv);

  // stage proj + x = q-chunk + dsm
  for (int i = tid; i < 2048; i += 512){
    int m = i >> 3, c8 = i & 7;
    int rgn = ((m>>5)*4 + (c8>>1))*2 + (c8&1);
    int slot = (m & 31) ^ ((rgn & 7) << 2);
    *(uint4*)(Bp + rgn*512 + slot*16) = *(const uint4*)(pjh + m*64 + c8*8);
  }
  #pragma unroll
  for (int it = 0; it < 4; ++it){
    int g = it*512 + tid;
    int row = g >> 4, c4 = g & 15;
    float4 xv = *(const float4*)(q + (size_t)(row0+row)*64 + c4*4);
    _Float16 h0=(_Float16)xv.x, h1=(_Float16)xv.y, h2=(_Float16)xv.z, h3=(_Float16)xv.w;
    float l0 = xv.x-(float)h0, l1 = xv.y-(float)h1, l2 = xv.z-(float)h2, l3 = xv.w-(float)h3;
    int rgn = ((row>>5)*4 + (c4>>2))*2 + ((c4>>1)&1);
    int off = rgn*512 + (((row&31) ^ ((c4>>1)<<2)))*16 + (c4&1)*8;
    uint2 ph; ph.x = (unsigned)h2u(h0)|((unsigned)h2u(h1)<<16);
              ph.y = (unsigned)h2u(h2)|((unsigned)h2u(h3)<<16);
    uint2 pl; pl.x = pk2h(l0,l1); pl.y = pk2h(l2,l3);
    *(uint2*)(Xh + off) = ph;
    *(uint2*)(Xl + off) = pl;
    float ssq = xv.x*xv.x + xv.y*xv.y + xv.z*xv.z + xv.w*xv.w;
    ssq += __shfl_xor(ssq, 1); ssq += __shfl_xor(ssq, 2);
    ssq += __shfl_xor(ssq, 4); ssq += __shfl_xor(ssq, 8);
    if ((tid & 15) == 0) dsm[row] = ssq;
  }
  __syncthreads();

  // q-dash
  f16x8 ah[4], al[4];
  #pragma unroll
  for (int ks = 0; ks < 4; ++ks){
    int rgn = (wr*4+ks)*2+half;
    int off = rgn*512 + ((l31 ^ ((2*ks+half)<<2)))*16;
    ah[ks] = *(const f16x8*)(Xh + off);
    al[ks] = *(const f16x8*)(Xl + off);
  }
  f32x16 acc[4];
  #pragma unroll
  for (int ct=0; ct<4; ++ct){
    #pragma unroll
    for (int r=0; r<16; ++r) acc[ct][r] = 0.f;
  }
  #pragma unroll
  for (int ks = 0; ks < 4; ++ks){
    #pragma unroll
    for (int ct=0; ct<4; ++ct){
      int ctg = wc*4 + ct;
      int rgn = (ctg*4+ks)*2+half;
      f16x8 bv = *(const f16x8*)(Bp + rgn*512 + ((l31 ^ ((2*ks+half)<<2)))*16);
      acc[ct] = __builtin_amdgcn_mfma_f32_32x32x16_f16(ah[ks], bv, acc[ct], 0, 0, 0);
      acc[ct] = __builtin_amdgcn_mfma_f32_32x32x16_f16(al[ks], bv, acc[ct], 0, 0, 0);
    }
  }
  // per-row max over this wave's 128 cols -> rmx
  {
    float rmax[16];
    #pragma unroll
    for (int r=0; r<16; ++r){
      float mx = acc[0][r];
      #pragma unroll
      for (int ct=1; ct<4; ++ct) mx = fmaxf(mx, acc[ct][r]);
      #pragma unroll
      for (int s=1; s<32; s<<=1) mx = fmaxf(mx, __shfl_xor(mx, s));
      rmax[r] = mx;
    }
    if (l31 == 0){
      #pragma unroll
      for (int r=0; r<16; ++r)
        rmx[wc*128 + 32*wr + (r&3) + 8*(r>>2) + 4*half] = rmax[r];
    }
  }
  __syncthreads();

  // epilogue-q: write qfb + qz partials
  float qzp[16];
  #pragma unroll
  for (int r=0;r<16;++r) qzp[r] = 0.f;
  {
    float dgv[16], stv[16];
    #pragma unroll
    for (int r=0; r<16; ++r){
      int lrow = 32*wr + (r&3) + 8*(r>>2) + 4*half;
      dgv[r] = DIAGC * dsm[lrow];
      stv[r] = fmaxf(rmx[lrow], rmx[128+lrow]);
    }
    #pragma unroll
    for (int ct=0; ct<4; ++ct){
      int m = wc*128 + ct*32 + l31;
      float z0v = Zp[(size_t)pb*256 + m] + AEPS;
      #pragma unroll
      for (int r=0; r<16; ++r){
        int c = 32*wr + (r&3) + 8*(r>>2) + 4*half;
        float e = __expf(acc[ct][r] - dgv[r] - stv[r]);
        unsigned b = f2bf(RATIO*(e + KEPS));
        *(ushort_t*)(qfb + c*512 + ((m*2) ^ ((c&15)<<4))) = (ushort_t)b;
        qzp[r] += bf2f((ushort_t)b) * z0v;
      }
    }
    #pragma unroll
    for (int s=1; s<32; s<<=1){
      #pragma unroll
      for (int r=0;r<16;++r) qzp[r] += __shfl_xor(qzp[r], s);
    }
    if (l31 == 0){
      #pragma unroll
      for (int r=0;r<16;++r)
        qzc[wc*128 + 32*wr + (r&3) + 8*(r>>2) + 4*half] = qzp[r];
    }
  }

  // m-loop: A = qf*kf^T (triangle) and acc2 = qf*S0
  f32x16 accA[2], acc2;
  #pragma unroll
  for (int ct2=0;ct2<2;++ct2){
    #pragma unroll
    for (int r=0;r<16;++r) accA[ct2][r] = 0.f;
  }
  #pragma unroll
  for (int r=0;r<16;++r) acc2[r] = 0.f;

  int arow = 32*wr + l31;
  for (int mt=0; mt<4; ++mt){
    int m0 = mt*64;
    __syncthreads();
    // stage ktb (corrected kf)
    #pragma unroll
    for (int u=0;u<2;++u){
      int ci = tid*2+u; int rr = ci>>3, c8 = ci&7;
      int sw = (c8*16) ^ ((rr&7)<<4);
      uint4 rk = *(const uint4*)(kfp + qbase + (size_t)rr*256 + m0 + c8*8);
      uint4 ck; ck.x = cvt2(rk.x, alpha); ck.y = cvt2(rk.y, alpha);
                ck.z = cvt2(rk.z, alpha); ck.w = cvt2(rk.w, alpha);
      *(uint4*)(ktb + rr*128 + sw) = ck;
    }
    // stage s0t
    {
      int mm = tid >> 3, c8 = tid & 7;
      uint4 sv = *(const uint4*)(S0b + (size_t)pb*16384 + (size_t)(m0+mm)*64 + c8*8);
      unsigned wds[4] = {sv.x, sv.y, sv.z, sv.w};
      #pragma unroll
      for (int jj=0;jj<4;++jj){
        int e0 = c8*8 + jj*2, e1 = e0 + 1;
        int sw0 = ((e0&7) ^ ((e0>>3)&7)) << 4;
        int sw1 = ((e1&7) ^ ((e1>>3)&7)) << 4;
        *(ushort_t*)(s0t + e0*128 + ((mm*2) ^ sw0)) = (ushort_t)(wds[jj] & 0xffffu);
        *(ushort_t*)(s0t + e1*128 + ((mm*2) ^ sw1)) = (ushort_t)(wds[jj] >> 16);
      }
    }
    __syncthreads();
    #pragma unroll
    for (int ks=0;ks<4;++ks){
      bf16x8 af = *(const bf16x8*)(qfb + arow*512 + ((m0*2 + ks*32 + half*16) ^ ((arow&15)<<4)));
      {
        int er = wc*32 + l31;
        int sw = ((er&7) ^ ((er>>3)&7)) << 4;
        bf16x8 bS = *(const bf16x8*)(s0t + er*128 + ((ks*32 + half*16) ^ sw));
        acc2 = __builtin_amdgcn_mfma_f32_32x32x16_bf16(af, bS, acc2, 0, 0, 0);
      }
      #pragma unroll
      for (int ct2=0;ct2<2;++ct2){
        int c = wc*2 + ct2;
        if (c <= wr){
          int br = c*32 + l31;
          bf16x8 bfv = *(const bf16x8*)(ktb + br*128 + ((ks*32 + half*16) ^ ((br&7)<<4)));
          accA[ct2] = __builtin_amdgcn_mfma_f32_32x32x16_bf16(af, bfv, accA[ct2], 0, 0, 0);
        }
      }
    }
  }

  // mask A, rowsums, write Ab (over dead proj region)
  {
    float p[16];
    #pragma unroll
    for (int r=0;r<16;++r) p[r]=0.f;
    #pragma unroll
    for (int ct2=0;ct2<2;++ct2){
      int c = wc*2 + ct2;
      if (c <= wr){
        #pragma unroll
        for (int r=0;r<16;++r){
          int grow = 32*wr + (r&3) + 8*(r>>2) + 4*half;
          int col  = c*32 + l31;
          float mval = (col <= grow) ? accA[ct2][r] : 0.f;
          p[r] += mval;
          *(ushort_t*)(Ab + grow*256 + ((col*2) ^ ((grow&15)<<4))) = f2bf(mval);
        }
      }
    }
    #pragma unroll
    for (int s=1;s<32;s<<=1){
      #pragma unroll
      for (int r=0;r<16;++r) p[r] += __shfl_xor(p[r], s);
    }
    if (l31 == 0){
      #pragma unroll
      for (int r=0;r<16;++r)
        rsc[wc*128 + 32*wr + (r&3) + 8*(r>>2) + 4*half] = p[r];
    }
  }
  __syncthreads();

  // stage vTb (over dead ktb/s0t)
  {
    int e = tid & 63, c0 = tid >> 6;
    int swz = (e & 15) << 4;
    #pragma unroll
    for (int u=0; u<16; ++u){
      int c = c0 + u*8;
      *(ushort_t*)(vTb + e*256 + ((c*2) ^ swz)) = f2bf(v[(size_t)(row0+c)*64 + e]);
    }
  }
  __syncthreads();

  // A*v (triangle over ks)
  #pragma unroll
  for (int ks=0; ks<8; ++ks){
    if (ks <= 2*wr + 1){
      bf16x8 af = *(const bf16x8*)(Ab + arow*256 + ((ks*32 + half*16) ^ ((arow&15)<<4)));
      int er = wc*32 + l31;
      bf16x8 bfv = *(const bf16x8*)(vTb + er*256 + ((ks*32 + half*16) ^ ((er&15)<<4)));
      acc2 = __builtin_amdgcn_mfma_f32_32x32x16_bf16(af, bfv, acc2, 0, 0, 0);
    }
  }
  __syncthreads();
  if (tid < 128)
    rsf[tid] = 1.0f / (rsc[tid] + rsc[128+tid] + qzc[tid] + qzc[128+tid]);
  __syncthreads();
  #pragma unroll
  for (int r=0;r<16;++r){
    int grow = 32*wr + (r&3) + 8*(r>>2) + 4*half;
    int e = wc*32 + l31;
    outO[(size_t)(row0+grow)*64 + e] = acc2[r] * rsf[grow];
  }
}

extern "C" void kernel_launch(void* const* d_in, const int* in_sizes, int n_in,
                              void* d_out, int out_size, void* d_ws, size_t ws_size,
                              hipStream_t stream){
  (void)in_sizes; (void)n_in; (void)out_size; (void)ws_size;
  const float* q    = (const float*)d_in[0];
  const float* k    = (const float*)d_in[1];
  const float* v    = (const float*)d_in[2];
  const float* proj = (const float*)d_in[3];

  char* ws = (char*)d_ws;
  unsigned* kmax = (unsigned*)ws;                                   // @0
  float*    lmA  = (float*)(ws + 256);                              // 2048 B
  ushort_t* pjh  = (ushort_t*)(ws + 4096);                          // 32768 B
  ushort_t* kfp  = (ushort_t*)(ws + 65792);                         // 33554432 B
  float*    Zl   = (float*)(ws + 65792 + 33554432);                 // 524288 B
  float*    Sl   = (float*)(ws + 65792 + 33554432 + 524288);        // 33554432 B
  ushort_t* S0b  = (ushort_t*)(ws + 65792 + 67633152);              // 16777216 B
  float*    vsb  = (float*)(ws + 65792 + 67633152 + 16777216);      // 131072 B

  float* outO = (float*)d_out;
  float* outZ = outO + (size_t)2*8*4096*64;
  float* outS = outZ + 2*8*256;

  hipFuncSetAttribute((const void*)k_chunkF, hipFuncAttributeMaxDynamicSharedMemorySize, 148480);
  hipFuncSetAttribute((const void*)k_outF,   hipFuncAttributeMaxDynamicSharedMemorySize, 126976);

  k_prep  <<<1,     256, 0, stream>>>(proj, pjh, kmax);
  k_chunkF<<<512,   512, 148480, stream>>>(k, v, pjh, kfp, Zl, Sl, vsb, kmax, lmA);
  k_scan  <<<16*65, 256, 0, stream>>>(Zl, Sl, vsb, lmA, kmax, S0b, outZ, outS);
  k_outF  <<<512,   512, 126976, stream>>>(q, pjh, kfp, v, S0b, Zl, lmA, kmax, outO);
}